// Round 4
// baseline (451.694 us; speedup 1.0000x reference)
//
#include <hip/hip_runtime.h>
#include <stdint.h>

#define LTOT 20000
#define LPAD 20224   // 316*64 = 79*256
#define DV   4096
#define DH   1024
#define DE   100
#define NB   256
#define NUNITS (79 * 16)

using f32x4 = __attribute__((ext_vector_type(4))) float;
using s16x8 = __attribute__((ext_vector_type(8))) short;
using u32x2 = __attribute__((ext_vector_type(2))) uint32_t;
using u32x4 = __attribute__((ext_vector_type(4))) uint32_t;
using f16x2 = __attribute__((ext_vector_type(2))) _Float16;

static __device__ __forceinline__ short f2bf(float x){
  union{float f; uint32_t u;} v; v.f = x;
  uint32_t r = (v.u + 0x7fffu + ((v.u >> 16) & 1u)) >> 16;
  return (short)r;
}

static __device__ __forceinline__ uint32_t pack2bf(float x, float y){
#if __has_builtin(__builtin_amdgcn_cvt_pk_bf16_f32)
  return __builtin_bit_cast(uint32_t, __builtin_amdgcn_cvt_pk_bf16_f32(x, y));
#else
  return (uint32_t)(uint16_t)f2bf(x) | ((uint32_t)(uint16_t)f2bf(y) << 16);
#endif
}

static __device__ __forceinline__ float dot2acc(f16x2 a, float c){
#if __has_builtin(__builtin_amdgcn_fdot2)
  return __builtin_amdgcn_fdot2(a, a, c, false);
#else
  float x = (float)a[0], y = (float)a[1];
  return __builtin_fmaf(x, x, __builtin_fmaf(y, y, c));
#endif
}

static __device__ __forceinline__ uint32_t actr_load(uint32_t* p){
  return __hip_atomic_load(p, __ATOMIC_RELAXED, __HIP_MEMORY_SCOPE_AGENT);
}
static __device__ __forceinline__ void actr_add(uint32_t* p){
  __hip_atomic_fetch_add(p, 1u, __ATOMIC_RELEASE, __HIP_MEMORY_SCOPE_AGENT);
}

// ctr[0]=done_gemm1(512) ctr[1]=done_e2t(256) ctr[2]=done_lvt(240)
// ctr[3]=done_w2t(16)    ctr[4]=score queue head
//
// One dispatch, stream-k-style dependency chaining (NO grid.sync -- r2 showed
// whole-grid barriers idle everything; here only true dependents wait, with
// s_sleep spins). __launch_bounds__(256,4): VGPR<=128 + LDS 25.9KB -> HW-
// guaranteed 4 blocks/CU -> all 1024 blocks co-resident -> spins can't
// deadlock. Cross-XCD visibility: release = __threadfence() + atomic add
// (agent scope); acquire = relaxed spin + __threadfence() (L2 inv).
__global__ __launch_bounds__(256, 4) void mega2(
    const float* __restrict__ vfs,  const float* __restrict__ W1,
    float* __restrict__ Hp,         const float* __restrict__ lab,
    uint32_t* __restrict__ lvT,     const float* __restrict__ W2,
    float* __restrict__ W2T,        const float* __restrict__ b1,
    const float* __restrict__ b2,   uint32_t* __restrict__ E2T,
    float* __restrict__ out,        uint32_t* __restrict__ ctr){
  __shared__ __align__(16) char smem[64 * 101 * 4];   // 25,856 B union
  __shared__ uint32_t tick;
  int t = threadIdx.x;
  int bx = blockIdx.x;

  if (bx < 512){
    // ---- GEMM1 tile (r3 verified body): Hp[kt] = bf16(relu(vfs))@bf16(W1)
    uint32_t* SU = (uint32_t*)smem;
    int kt = bx & 7, nt = (bx >> 3) & 15, mt = bx >> 7;
    int lane = t & 63, wv = t >> 6;
    int wm = wv >> 1, wn = wv & 1;
    int col = lane & 15, quad = lane >> 4;

    f32x4 acc00 = {}, acc01 = {}, acc10 = {}, acc11 = {};

    int rA = t >> 2, c4 = t & 3;
    const float* aPtr = vfs + (size_t)(mt * 64 + rA) * DV + kt * 512 + c4 * 8;
    int k2 = t & 15, n4 = t >> 4;
    const float* bPtr = W1 + (size_t)(kt * 512 + 2 * k2) * DH + nt * 64 + n4 * 4;

    f32x4 a0, a1, b0, b1v;
    u32x4 apk, bpk;

#define CVT_AB() do{ \
    apk[0] = pack2bf(__builtin_fmaxf(a0[0],0.f), __builtin_fmaxf(a0[1],0.f)); \
    apk[1] = pack2bf(__builtin_fmaxf(a0[2],0.f), __builtin_fmaxf(a0[3],0.f)); \
    apk[2] = pack2bf(__builtin_fmaxf(a1[0],0.f), __builtin_fmaxf(a1[1],0.f)); \
    apk[3] = pack2bf(__builtin_fmaxf(a1[2],0.f), __builtin_fmaxf(a1[3],0.f)); \
    bpk[0] = pack2bf(b0[0], b1v[0]); bpk[1] = pack2bf(b0[1], b1v[1]); \
    bpk[2] = pack2bf(b0[2], b1v[2]); bpk[3] = pack2bf(b0[3], b1v[3]); }while(0)

#define LOAD_SLAB(s) do{ \
    a0  = *(const f32x4*)(aPtr + (s) * 32); \
    a1  = *(const f32x4*)(aPtr + (s) * 32 + 4); \
    b0  = *(const f32x4*)(bPtr + (size_t)(s) * 32 * DH); \
    b1v = *(const f32x4*)(bPtr + (size_t)(s) * 32 * DH + DH); }while(0)

#define STORE_SLAB(buf) do{ \
    uint32_t* As_ = SU + (buf) * 2560; \
    uint32_t* Bs_ = As_ + 1280; \
    *(u32x4*)&As_[rA * 20 + c4 * 4] = apk; \
    Bs_[(n4 * 4 + 0) * 20 + k2] = bpk[0]; \
    Bs_[(n4 * 4 + 1) * 20 + k2] = bpk[1]; \
    Bs_[(n4 * 4 + 2) * 20 + k2] = bpk[2]; \
    Bs_[(n4 * 4 + 3) * 20 + k2] = bpk[3]; }while(0)

    LOAD_SLAB(0);
    CVT_AB();
    STORE_SLAB(0);
    LOAD_SLAB(1);
    __syncthreads();

    for (int it = 0; it < 16; ++it){
      const short* AsS = (const short*)(SU + (it & 1) * 2560);     // [64][40]
      const short* BsS = (const short*)(SU + (it & 1) * 2560 + 1280);

      s16x8 af0 = *(const s16x8*)&AsS[(wm * 32 + col) * 40 + quad * 8];
      s16x8 af1 = *(const s16x8*)&AsS[(wm * 32 + 16 + col) * 40 + quad * 8];
      s16x8 bf0 = *(const s16x8*)&BsS[(wn * 32 + col) * 40 + quad * 8];
      s16x8 bf1 = *(const s16x8*)&BsS[(wn * 32 + 16 + col) * 40 + quad * 8];

      acc00 = __builtin_amdgcn_mfma_f32_16x16x32_bf16(af0, bf0, acc00, 0, 0, 0);
      acc01 = __builtin_amdgcn_mfma_f32_16x16x32_bf16(af0, bf1, acc01, 0, 0, 0);
      acc10 = __builtin_amdgcn_mfma_f32_16x16x32_bf16(af1, bf0, acc10, 0, 0, 0);
      acc11 = __builtin_amdgcn_mfma_f32_16x16x32_bf16(af1, bf1, acc11, 0, 0, 0);

      if (it < 15){
        CVT_AB();
        STORE_SLAB((it + 1) & 1);
        if (it < 14) LOAD_SLAB(it + 2);
      }
      __syncthreads();
    }
#undef LOAD_SLAB
#undef STORE_SLAB
#undef CVT_AB

    float* hp = Hp + (size_t)kt * NB * DH;
    int rbase = mt * 64 + wm * 32 + quad * 4;
    int cbase = nt * 64 + wn * 32 + col;
    #pragma unroll
    for (int r = 0; r < 4; ++r){
      hp[(size_t)(rbase + r) * DH + cbase]           = acc00[r];
      hp[(size_t)(rbase + r) * DH + cbase + 16]      = acc01[r];
      hp[(size_t)(rbase + 16 + r) * DH + cbase]      = acc10[r];
      hp[(size_t)(rbase + 16 + r) * DH + cbase + 16] = acc11[r];
    }
    __threadfence();                     // release Hp
    if (t == 0) actr_add(&ctr[0]);

    if (bx < 256){
      // ---- gemm2 duty: row n = bx, once all Hp + W2T are visible ----
      if (t == 0){
        while (actr_load(&ctr[0]) < 512u || actr_load(&ctr[3]) < 16u)
          __builtin_amdgcn_s_sleep(2);
      }
      __syncthreads();
      __threadfence();                   // acquire (invalidate stale L2)

      float* hs = (float*)smem;          // [1024]
      float (*red)[64][2] = (float(*)[64][2])(smem + 4096);
      int n = bx;

      f32x4 hv = {};
      #pragma unroll
      for (int kt2 = 0; kt2 < 8; ++kt2)
        hv += *(const f32x4*)&Hp[(size_t)kt2 * NB * DH + (size_t)n * DH + t * 4];
      f32x4 bv = *(const f32x4*)&b1[t * 4];
      f32x4 hr;
      #pragma unroll
      for (int i = 0; i < 4; ++i) hr[i] = __builtin_fmaxf(hv[i] + bv[i], 0.f);
      *(f32x4*)&hs[t * 4] = hr;
      __syncthreads();

      int d2 = t & 63, ks = t >> 6;
      float a00 = 0.f, a01 = 0.f, a10 = 0.f, a11 = 0.f;
      if (d2 < 50){
        const float* w0 = W2T + (size_t)(2 * d2) * DH + ks * 256;
        const float* w1 = w0 + DH;
        const float* hq = hs + ks * 256;
        #pragma unroll 4
        for (int kk = 0; kk < 256; kk += 8){
          f32x4 h0 = *(const f32x4*)(hq + kk);
          f32x4 h1 = *(const f32x4*)(hq + kk + 4);
          f32x4 wa = *(const f32x4*)(w0 + kk);
          f32x4 wb = *(const f32x4*)(w0 + kk + 4);
          f32x4 wc = *(const f32x4*)(w1 + kk);
          f32x4 wd = *(const f32x4*)(w1 + kk + 4);
          #pragma unroll
          for (int i = 0; i < 4; ++i){
            a00 = __builtin_fmaf(wa[i], h0[i], a00);
            a01 = __builtin_fmaf(wb[i], h1[i], a01);
            a10 = __builtin_fmaf(wc[i], h0[i], a10);
            a11 = __builtin_fmaf(wd[i], h1[i], a11);
          }
        }
      }
      red[ks][d2][0] = a00 + a01;
      red[ks][d2][1] = a10 + a11;
      __syncthreads();
      if (t < 50){
        float s0 = red[0][t][0] + red[1][t][0] + red[2][t][0] + red[3][t][0] + b2[2 * t];
        float s1 = red[0][t][1] + red[1][t][1] + red[2][t][1] + red[3][t][1] + b2[2 * t + 1];
        E2T[(size_t)t * NB + n] =
            __builtin_bit_cast(uint32_t, __builtin_amdgcn_cvt_pkrtz(s0, s1));
      }
      __threadfence();                   // release E2T
      if (t == 0) actr_add(&ctr[1]);
    }
  } else if (bx < 752){
    // ---- lvT transpose: 316 64-row tiles over 240 blocks ----
    float* T = (float*)smem;
    for (int uu = bx - 512; uu < 316; uu += 240){
      int lbase = uu * 64;
      for (int i = t; i < 64 * 100; i += 256){
        int lloc = i / 100;
        int d = i - lloc * 100;
        int l = lbase + lloc;
        T[lloc * 101 + d] = (l < LTOT) ? lab[(size_t)l * DE + d] : 0.f;
      }
      __syncthreads();
      for (int j = t; j < 64 * 50; j += 256){
        int lloc = j & 63, d2 = j >> 6;
        f16x2 p;
        p[0] = (_Float16)T[lloc * 101 + 2 * d2];
        p[1] = (_Float16)T[lloc * 101 + 2 * d2 + 1];
        lvT[(size_t)d2 * LPAD + lbase + lloc] = __builtin_bit_cast(uint32_t, p);
      }
      __syncthreads();                   // T reuse across units
    }
    __threadfence();                     // release lvT
    if (t == 0) actr_add(&ctr[2]);
  } else if (bx < 768){
    // ---- W2 [1024][100] -> W2T [100][1024], 64-row tiles ----
    float* T = (float*)smem;
    int k0 = (bx - 752) * 64;
    for (int i = t; i < 64 * 100; i += 256){
      int kk = i / 100;
      int d = i - kk * 100;
      T[kk * 101 + d] = W2[(size_t)(k0 + kk) * DE + d];
    }
    __syncthreads();
    for (int i = t; i < 100 * 64; i += 256){
      int d = i >> 6, kk = i & 63;
      W2T[(size_t)d * DH + k0 + kk] = T[kk * 101 + d];
    }
    __threadfence();                     // release W2T
    if (t == 0) actr_add(&ctr[3]);
  }
  // bx 768..1023: spare blocks go straight to the scores queue.

  // ---- scores work-queue: 1264 units, gated once on E2T + lvT ready ----
  bool ready = false;
  for (;;){
    if (t == 0)
      tick = __hip_atomic_fetch_add(&ctr[4], 1u, __ATOMIC_RELAXED,
                                    __HIP_MEMORY_SCOPE_AGENT);
    __syncthreads();
    uint32_t u = tick;
    __syncthreads();                     // tick consumed before next write
    if (u >= (uint32_t)NUNITS) break;

    if (!ready){
      if (t == 0){
        while (actr_load(&ctr[1]) < 256u || actr_load(&ctr[2]) < 240u)
          __builtin_amdgcn_s_sleep(2);
      }
      __syncthreads();
      __threadfence();                   // acquire E2T / lvT
      ready = true;
    }

    int lt = (int)u % 79, ntile = (int)u / 79;
    int l = lt * 256 + t;
    int n0 = ntile * 16;

    float acc[16];
    #pragma unroll
    for (int i = 0; i < 16; ++i) acc[i] = 0.f;

    f16x2 z = {(_Float16)0, (_Float16)0};
    const uint32_t* lp = lvT + l;
    const uint32_t* ep = E2T + n0;       // block-uniform -> s_load

    #pragma unroll 2
    for (int d2 = 0; d2 < 50; ++d2){
      f16x2 lv = __builtin_bit_cast(f16x2, lp[(size_t)d2 * LPAD]);
      #pragma unroll
      for (int i = 0; i < 16; ++i){
        f16x2 ev = __builtin_bit_cast(f16x2, ep[(size_t)d2 * NB + i]);
        f16x2 df = lv - ev;
        df = __builtin_elementwise_max(df, z);
        acc[i] = dot2acc(df, acc[i]);
      }
    }

    if (l < LTOT){
      float* op = out + (size_t)n0 * LTOT + l;
      #pragma unroll
      for (int i = 0; i < 16; ++i)
        op[(size_t)i * LTOT] = -__builtin_sqrtf(acc[i]);
    }
  }
}

// ---------------------------------------------------------------------------
extern "C" void kernel_launch(void* const* d_in, const int* in_sizes, int n_in,
                              void* d_out, int out_size, void* d_ws, size_t ws_size,
                              hipStream_t stream){
  const float* vfs = (const float*)d_in[0];
  const float* lab = (const float*)d_in[1];
  const float* W1  = (const float*)d_in[2];
  const float* b1  = (const float*)d_in[3];
  const float* W2  = (const float*)d_in[4];
  const float* b2  = (const float*)d_in[5];
  float* out = (float*)d_out;

  char* ws = (char*)d_ws;
  uint32_t* lvT = (uint32_t*)ws;                    //  4,044,800 B [50][LPAD]
  float*    Hp  = (float*)(ws + 4044800);           //  8,388,608 B [8][256][1024]
  uint32_t* E2T = (uint32_t*)(ws + 12433408);       //     51,200 B [50][256]
  float*    W2T = (float*)(ws + 12484608);          //    409,600 B [100][1024]
  uint32_t* ctr = (uint32_t*)(ws + 12894208);       //         32 B counters

  hipMemsetAsync(ctr, 0, 32, stream);
  mega2<<<1024, 256, 0, stream>>>(vfs, W1, Hp, lab, lvT, W2, W2T,
                                  b1, b2, E2T, out, ctr);
}

// Round 5
// 145.103 us; speedup vs baseline: 3.1129x; 3.1129x over previous
//
#include <hip/hip_runtime.h>
#include <stdint.h>

#define LTOT 20000
#define LPAD 20224   // 316*64 = 79*256
#define DV   4096
#define DH   1024
#define DE   100
#define NB   256

using f32x2 = __attribute__((ext_vector_type(2))) float;
using f32x4 = __attribute__((ext_vector_type(4))) float;
using s16x8 = __attribute__((ext_vector_type(8))) short;
using u32x2 = __attribute__((ext_vector_type(2))) uint32_t;
using u32x4 = __attribute__((ext_vector_type(4))) uint32_t;
using f16x2 = __attribute__((ext_vector_type(2))) _Float16;

static __device__ __forceinline__ short f2bf(float x){
  union{float f; uint32_t u;} v; v.f = x;
  uint32_t r = (v.u + 0x7fffu + ((v.u >> 16) & 1u)) >> 16;
  return (short)r;
}

// pack two f32 -> two bf16 (RTNE)
static __device__ __forceinline__ uint32_t pack2bf(float x, float y){
#if __has_builtin(__builtin_amdgcn_cvt_pk_bf16_f32)
  return __builtin_bit_cast(uint32_t, __builtin_amdgcn_cvt_pk_bf16_f32(x, y));
#else
  return (uint32_t)(uint16_t)f2bf(x) | ((uint32_t)(uint16_t)f2bf(y) << 16);
#endif
}

static __device__ __forceinline__ float dot2acc(f16x2 a, float c){
#if __has_builtin(__builtin_amdgcn_fdot2)
  return __builtin_amdgcn_fdot2(a, a, c, false);
#else
  float x = (float)a[0], y = (float)a[1];
  return __builtin_fmaf(x, x, __builtin_fmaf(y, y, c));
#endif
}

// ---------------------------------------------------------------------------
// Kernel 1 (fused): GEMM1 + independent prep work in one dispatch.
// (verbatim r3-verified body)
//   blocks 0..511  : Hp[kt] = bf16(relu(vfs)) @ bf16(W1)  (64x64 tiles,
//                    split-K=8, plain stores to per-kt partials).
//                    LDS DOUBLE-BUFFERED k-slabs, loads issued 2 iters ahead,
//                    ONE barrier per K-step. 25.9 KB LDS union -> 6 blocks/CU.
//   blocks 512..827: label_vecs -> lvT [50][LPAD] half2 (64-row tiles, 316)
//   blocks 828..843: W2 [1024][100] -> W2T [100][1024] f32 (64-row tiles, 16)
// ---------------------------------------------------------------------------
__global__ __launch_bounds__(256) void fused_k(const float* __restrict__ vfs,
                                               const float* __restrict__ W1,
                                               float* __restrict__ Hp,
                                               const float* __restrict__ lab,
                                               uint32_t* __restrict__ lvT,
                                               const float* __restrict__ W2,
                                               float* __restrict__ W2T){
  __shared__ __align__(16) char smem[64 * 101 * 4];   // 25,856 B union
  int t = threadIdx.x;
  int bx = blockIdx.x;

  if (bx < 512){
    // ---- GEMM1 tile: kt = bx&7, nt = (bx>>3)&15, mt = bx>>7 ----
    uint32_t* SU = (uint32_t*)smem;

    int kt = bx & 7, nt = (bx >> 3) & 15, mt = bx >> 7;
    int lane = t & 63, wv = t >> 6;
    int wm = wv >> 1, wn = wv & 1;
    int col = lane & 15, quad = lane >> 4;

    f32x4 acc00 = {}, acc01 = {}, acc10 = {}, acc11 = {};

    int rA = t >> 2, c4 = t & 3;
    const float* aPtr = vfs + (size_t)(mt * 64 + rA) * DV + kt * 512 + c4 * 8;
    int k2 = t & 15, n4 = t >> 4;
    const float* bPtr = W1 + (size_t)(kt * 512 + 2 * k2) * DH + nt * 64 + n4 * 4;

    f32x4 a0, a1, b0, b1v;
    u32x4 apk, bpk;

#define CVT_AB() do{ \
    apk[0] = pack2bf(__builtin_fmaxf(a0[0],0.f), __builtin_fmaxf(a0[1],0.f)); \
    apk[1] = pack2bf(__builtin_fmaxf(a0[2],0.f), __builtin_fmaxf(a0[3],0.f)); \
    apk[2] = pack2bf(__builtin_fmaxf(a1[0],0.f), __builtin_fmaxf(a1[1],0.f)); \
    apk[3] = pack2bf(__builtin_fmaxf(a1[2],0.f), __builtin_fmaxf(a1[3],0.f)); \
    bpk[0] = pack2bf(b0[0], b1v[0]); bpk[1] = pack2bf(b0[1], b1v[1]); \
    bpk[2] = pack2bf(b0[2], b1v[2]); bpk[3] = pack2bf(b0[3], b1v[3]); }while(0)

#define LOAD_SLAB(s) do{ \
    a0  = *(const f32x4*)(aPtr + (s) * 32); \
    a1  = *(const f32x4*)(aPtr + (s) * 32 + 4); \
    b0  = *(const f32x4*)(bPtr + (size_t)(s) * 32 * DH); \
    b1v = *(const f32x4*)(bPtr + (size_t)(s) * 32 * DH + DH); }while(0)

#define STORE_SLAB(buf) do{ \
    uint32_t* As_ = SU + (buf) * 2560; \
    uint32_t* Bs_ = As_ + 1280; \
    *(u32x4*)&As_[rA * 20 + c4 * 4] = apk; \
    Bs_[(n4 * 4 + 0) * 20 + k2] = bpk[0]; \
    Bs_[(n4 * 4 + 1) * 20 + k2] = bpk[1]; \
    Bs_[(n4 * 4 + 2) * 20 + k2] = bpk[2]; \
    Bs_[(n4 * 4 + 3) * 20 + k2] = bpk[3]; }while(0)

    LOAD_SLAB(0);
    CVT_AB();
    STORE_SLAB(0);
    LOAD_SLAB(1);            // in flight across the barrier + first MFMAs
    __syncthreads();

    for (int it = 0; it < 16; ++it){
      const short* AsS = (const short*)(SU + (it & 1) * 2560);     // [64][40]
      const short* BsS = (const short*)(SU + (it & 1) * 2560 + 1280);

      s16x8 af0 = *(const s16x8*)&AsS[(wm * 32 + col) * 40 + quad * 8];
      s16x8 af1 = *(const s16x8*)&AsS[(wm * 32 + 16 + col) * 40 + quad * 8];
      s16x8 bf0 = *(const s16x8*)&BsS[(wn * 32 + col) * 40 + quad * 8];
      s16x8 bf1 = *(const s16x8*)&BsS[(wn * 32 + 16 + col) * 40 + quad * 8];

      acc00 = __builtin_amdgcn_mfma_f32_16x16x32_bf16(af0, bf0, acc00, 0, 0, 0);
      acc01 = __builtin_amdgcn_mfma_f32_16x16x32_bf16(af0, bf1, acc01, 0, 0, 0);
      acc10 = __builtin_amdgcn_mfma_f32_16x16x32_bf16(af1, bf0, acc10, 0, 0, 0);
      acc11 = __builtin_amdgcn_mfma_f32_16x16x32_bf16(af1, bf1, acc11, 0, 0, 0);

      if (it < 15){
        CVT_AB();                       // waits on loads issued last iteration
        STORE_SLAB((it + 1) & 1);       // other buffer: no race with reads
        if (it < 14) LOAD_SLAB(it + 2); // 2-ahead issue: full iter of slack
      }
      __syncthreads();                  // one barrier per K-step
    }
#undef LOAD_SLAB
#undef STORE_SLAB
#undef CVT_AB

    float* hp = Hp + (size_t)kt * NB * DH;   // per-kt partial, plain stores
    int rbase = mt * 64 + wm * 32 + quad * 4;
    int cbase = nt * 64 + wn * 32 + col;
    #pragma unroll
    for (int r = 0; r < 4; ++r){
      hp[(size_t)(rbase + r) * DH + cbase]           = acc00[r];
      hp[(size_t)(rbase + r) * DH + cbase + 16]      = acc01[r];
      hp[(size_t)(rbase + 16 + r) * DH + cbase]      = acc10[r];
      hp[(size_t)(rbase + 16 + r) * DH + cbase + 16] = acc11[r];
    }
  } else if (bx < 828){
    // ---- label_vecs -> lvT [50][LPAD] half2, 64-row tiles (316 tiles) ----
    float* T = (float*)smem;
    int lbase = (bx - 512) * 64;
    for (int i = t; i < 64 * 100; i += 256){
      int lloc = i / 100;
      int d = i - lloc * 100;
      int l = lbase + lloc;
      T[lloc * 101 + d] = (l < LTOT) ? lab[(size_t)l * DE + d] : 0.f;
    }
    __syncthreads();
    for (int j = t; j < 64 * 50; j += 256){
      int lloc = j & 63, d2 = j >> 6;
      f16x2 p;
      p[0] = (_Float16)T[lloc * 101 + 2 * d2];
      p[1] = (_Float16)T[lloc * 101 + 2 * d2 + 1];
      lvT[(size_t)d2 * LPAD + lbase + lloc] = __builtin_bit_cast(uint32_t, p);
    }
  } else {
    // ---- W2 [1024][100] -> W2T [100][1024], 64-row tiles (16 tiles) ----
    float* T = (float*)smem;
    int k0 = (bx - 828) * 64;
    for (int i = t; i < 64 * 100; i += 256){
      int kk = i / 100;
      int d = i - kk * 100;
      T[kk * 101 + d] = W2[(size_t)(k0 + kk) * DE + d];
    }
    __syncthreads();
    for (int i = t; i < 100 * 64; i += 256){
      int d = i >> 6, kk = i & 63;
      W2T[(size_t)d * DH + k0 + kk] = T[kk * 101 + d];
    }
  }
}

// ---------------------------------------------------------------------------
// Kernel 2: E2T = pack_f16( relu(sum_kt Hp[kt] + b1) @ W2 + b2 ) TRANSPOSED
// [50][256] half2. 256 blocks x 512 THREADS (was 256): 8 waves/CU instead of
// 4 -- the kt-sum (8 dependent loads) and strided W2T rows are latency-
// exposed at 1 block/CU; doubling waves + halving per-thread serial work
// attacks that directly. ks in [0,8) x 128-k slices, red[8][64][2].
// ---------------------------------------------------------------------------
__global__ __launch_bounds__(512) void gemm2(const float* __restrict__ Hp,
                                             const float* __restrict__ b1,
                                             const float* __restrict__ W2T,
                                             const float* __restrict__ b2,
                                             uint32_t* __restrict__ E2T){
  __shared__ float hs[DH];
  __shared__ float red[8][64][2];
  int t = threadIdx.x;                 // 0..511
  int n = blockIdx.x;

  // sum split-K partials: float2 per thread (512 thr x 2 = 1024)
  f32x2 hv = {};
  #pragma unroll
  for (int kt = 0; kt < 8; ++kt)
    hv += *(const f32x2*)&Hp[(size_t)kt * NB * DH + (size_t)n * DH + t * 2];
  f32x2 bv = *(const f32x2*)&b1[t * 2];
  f32x2 hr;
  hr[0] = __builtin_fmaxf(hv[0] + bv[0], 0.f);
  hr[1] = __builtin_fmaxf(hv[1] + bv[1], 0.f);
  *(f32x2*)&hs[t * 2] = hr;
  __syncthreads();

  int d2 = t & 63, ks = t >> 6;        // ks 0..7 -> 128-k slice, uniform hs
  float a00 = 0.f, a01 = 0.f, a10 = 0.f, a11 = 0.f;
  if (d2 < 50){
    const float* w0 = W2T + (size_t)(2 * d2) * DH + ks * 128;
    const float* w1 = w0 + DH;
    const float* hp = hs + ks * 128;
    #pragma unroll 4
    for (int kk = 0; kk < 128; kk += 8){
      f32x4 h0 = *(const f32x4*)(hp + kk);
      f32x4 h1 = *(const f32x4*)(hp + kk + 4);
      f32x4 wa = *(const f32x4*)(w0 + kk);
      f32x4 wb = *(const f32x4*)(w0 + kk + 4);
      f32x4 wc = *(const f32x4*)(w1 + kk);
      f32x4 wd = *(const f32x4*)(w1 + kk + 4);
      #pragma unroll
      for (int i = 0; i < 4; ++i){
        a00 = __builtin_fmaf(wa[i], h0[i], a00);
        a01 = __builtin_fmaf(wb[i], h1[i], a01);
        a10 = __builtin_fmaf(wc[i], h0[i], a10);
        a11 = __builtin_fmaf(wd[i], h1[i], a11);
      }
    }
  }
  red[ks][d2][0] = a00 + a01;
  red[ks][d2][1] = a10 + a11;
  __syncthreads();
  if (t < 50){
    float s0 = b2[2 * t], s1 = b2[2 * t + 1];
    #pragma unroll
    for (int ks2 = 0; ks2 < 8; ++ks2){
      s0 += red[ks2][t][0];
      s1 += red[ks2][t][1];
    }
    // transposed: E2T[d2][n] so scores_k reads 16 consecutive n per s_load
    E2T[(size_t)t * NB + n] =
        __builtin_bit_cast(uint32_t, __builtin_amdgcn_cvt_pkrtz(s0, s1));
  }
}

// ---------------------------------------------------------------------------
// Kernel 3: scores[n][l] = -sqrt( sum_d relu(lv[l][d] - e[n][d])^2 )
// grid = (79 l-tiles, 16 n-tiles), 256 thr; d2 OUTER loop, 16 fp32 acc.
// NEW: explicit 5-deep register pipeline on the strided lv loads (cur/nxt
// groups of 5) -- 5 L2 loads in flight per wave instead of ~1-2, so the
// ~200-300cy L2 latency is covered by the 240 VALU ops per group even at
// ~5 waves/SIMD. All cur/nxt indices compile-time (no scratch).
// ---------------------------------------------------------------------------
__global__ __launch_bounds__(256) void scores_k(const uint32_t* __restrict__ lvT,
                                                const uint32_t* __restrict__ E2T,
                                                float* __restrict__ out){
  int t = threadIdx.x;
  int l = blockIdx.x * 256 + t;
  int n0 = blockIdx.y * 16;

  float acc[16];
  #pragma unroll
  for (int i = 0; i < 16; ++i) acc[i] = 0.f;

  f16x2 z = {(_Float16)0, (_Float16)0};
  const uint32_t* lp = lvT + l;
  const uint32_t* ep = E2T + n0;          // block-uniform -> s_load

  uint32_t cur[5], nxt[5];
  #pragma unroll
  for (int q = 0; q < 5; ++q) cur[q] = lp[(size_t)q * LPAD];

  #pragma unroll 2
  for (int g = 0; g < 10; ++g){
    if (g < 9){
      #pragma unroll
      for (int q = 0; q < 5; ++q) nxt[q] = lp[(size_t)((g + 1) * 5 + q) * LPAD];
    }
    #pragma unroll
    for (int q = 0; q < 5; ++q){
      f16x2 lv = __builtin_bit_cast(f16x2, cur[q]);
      int d2 = g * 5 + q;
      #pragma unroll
      for (int i = 0; i < 16; ++i){
        f16x2 ev = __builtin_bit_cast(f16x2, ep[(size_t)d2 * NB + i]);
        f16x2 df = lv - ev;
        df = __builtin_elementwise_max(df, z);
        acc[i] = dot2acc(df, acc[i]);
      }
    }
    #pragma unroll
    for (int q = 0; q < 5; ++q) cur[q] = nxt[q];
  }

  if (l < LTOT){
    float* op = out + (size_t)n0 * LTOT + l;
    #pragma unroll
    for (int i = 0; i < 16; ++i)
      op[(size_t)i * LTOT] = -__builtin_sqrtf(acc[i]);
  }
}

// ---------------------------------------------------------------------------
extern "C" void kernel_launch(void* const* d_in, const int* in_sizes, int n_in,
                              void* d_out, int out_size, void* d_ws, size_t ws_size,
                              hipStream_t stream){
  const float* vfs = (const float*)d_in[0];
  const float* lab = (const float*)d_in[1];
  const float* W1  = (const float*)d_in[2];
  const float* b1  = (const float*)d_in[3];
  const float* W2  = (const float*)d_in[4];
  const float* b2  = (const float*)d_in[5];
  float* out = (float*)d_out;

  char* ws = (char*)d_ws;
  uint32_t* lvT = (uint32_t*)ws;                    //  4,044,800 B [50][LPAD]
  float*    Hp  = (float*)(ws + 4044800);           //  8,388,608 B [8][256][1024]
  uint32_t* E2T = (uint32_t*)(ws + 12433408);       //     51,200 B [50][256]
  float*    W2T = (float*)(ws + 12484608);          //    409,600 B [100][1024]

  fused_k<<<844, 256, 0, stream>>>(vfs, W1, Hp, lab, lvT, W2, W2T);
  gemm2<<<256, 512, 0, stream>>>(Hp, b1, W2T, b2, E2T);
  scores_k<<<dim3(79, 16), 256, 0, stream>>>(lvT, E2T, out);
}